// Round 1
// baseline (860.181 us; speedup 1.0000x reference)
//
#include <hip/hip_runtime.h>

#define NN 14541
#define RR 64
#define EE 16384

typedef unsigned short u16;
typedef __attribute__((ext_vector_type(8))) short bf16x8;
typedef __attribute__((ext_vector_type(4))) float f32x4;

__device__ __forceinline__ u16 f2b(float f) {
  unsigned u = __builtin_bit_cast(unsigned, f);
  u += 0x7fffu + ((u >> 16) & 1u);
  return (u16)(u >> 16);
}
__device__ __forceinline__ float sigm(float x) { return 1.0f / (1.0f + expf(-x)); }

// ---------- degree count ----------
__global__ void deg_k(const int* __restrict__ src, const int* __restrict__ dst,
                      float* __restrict__ dout, float* __restrict__ din) {
  int i = blockIdx.x * 256 + threadIdx.x;   // exactly RR*EE threads
  int r = i >> 14;                          // E = 16384 = 2^14
  atomicAdd(&dout[r * NN + src[i]], 1.0f);
  atomicAdd(&din[r * NN + dst[i]], 1.0f);
}

// ---------- norms in place: deg -> deg^-0.5 (1.0 if deg==0) ----------
__global__ void norm_k(float* a, float* b) {
  int i = blockIdx.x * 256 + threadIdx.x;
  if (i >= RR * NN) return;
  float x = a[i]; a[i] = x > 0.f ? rsqrtf(x) : 1.0f;
  float y = b[i]; b[i] = y > 0.f ? rsqrtf(y) : 1.0f;
}

// ---------- weight transpose + bf16 convert ----------
// W1: [R][128 k][128 h] -> W1T: [R][128 h][128 k] bf16
__global__ void wt1_k(const float* __restrict__ W1, u16* __restrict__ W1T) {
  int idx = blockIdx.x * 256 + threadIdx.x;      // RR*128*128
  int r = idx >> 14, rem = idx & 16383, h = rem >> 7, k = rem & 127;
  W1T[idx] = f2b(W1[(r << 14) + (k << 7) + h]);
}
// W2: [R][128 k][64 o] -> W2T: [R][64 o][128 k] bf16
__global__ void wt2_k(const float* __restrict__ W2, u16* __restrict__ W2T) {
  int idx = blockIdx.x * 256 + threadIdx.x;      // RR*64*128
  int r = idx >> 13, rem = idx & 8191, o = rem >> 7, k = rem & 127;
  W2T[idx] = f2b(W2[(r << 13) + (k << 6) + o]);
}
__global__ void bias_k(const float* __restrict__ b1, const float* __restrict__ b2,
                       float* __restrict__ mb1, float* __restrict__ mb2) {
  int t = threadIdx.x;
  if (t < 128) { float s = 0.f; for (int r = 0; r < RR; r++) s += b1[r * 128 + t]; mb1[t] = s * (1.f/64.f); }
  if (t < 64)  { float s = 0.f; for (int r = 0; r < RR; r++) s += b2[r * 64 + t];  mb2[t] = s * (1.f/64.f); }
}

// ---------- conv1: per-WG = (relation, 128 edges); C[e][h] = x[src_e] @ W1[r]; scatter c_e*C[e] ----------
__global__ __launch_bounds__(256, 2) void conv1_k(
    const float* __restrict__ x, const int* __restrict__ src, const int* __restrict__ dst,
    const float* __restrict__ nout, const float* __restrict__ nin,
    const u16* __restrict__ W1T, float* __restrict__ out1)
{
  __shared__ __align__(16) u16 As[128 * 128];   // [edge][k] bf16, XOR-swizzled 16B units
  __shared__ __align__(16) u16 Bs[128 * 128];   // [h][k] bf16 (W^T), swizzled
  __shared__ float cb[128];
  __shared__ int   sb[128], db[128];

  const int tid = threadIdx.x;
  const int r = blockIdx.x >> 7, chunk = blockIdx.x & 127;
  const int ebase = r * EE + chunk * 128;

  if (tid < 128) {
    int s = src[ebase + tid], d = dst[ebase + tid];
    sb[tid] = s; db[tid] = d;
    cb[tid] = nout[r * NN + s] * nin[r * NN + d] * (1.0f / 64.0f);
  }
  // stage B = W1T[r] (32 KB), coalesced 16B, swizzle on write
  {
    const uint4* Bg = (const uint4*)(W1T + (r << 14));
    #pragma unroll
    for (int it = 0; it < 8; ++it) {
      int idx = it * 256 + tid;        // 2048 16B units
      int h = idx >> 4, u = idx & 15;
      *(uint4*)(Bs + h * 128 + ((u ^ (h & 7)) << 3)) = Bg[idx];
    }
  }
  __syncthreads();
  // stage A: gather x[src] rows, f32 -> bf16 (unscaled; c_e applied at scatter)
  {
    const int i = tid >> 1, half = tid & 1;
    const int s = sb[i];
    const float4* xs = (const float4*)(x + s * 128 + half * 64);
    #pragma unroll
    for (int q = 0; q < 8; ++q) {
      float4 v0 = xs[2 * q], v1 = xs[2 * q + 1];
      int u = half * 8 + q;
      bf16x8 t;
      t[0] = (short)f2b(v0.x); t[1] = (short)f2b(v0.y); t[2] = (short)f2b(v0.z); t[3] = (short)f2b(v0.w);
      t[4] = (short)f2b(v1.x); t[5] = (short)f2b(v1.y); t[6] = (short)f2b(v1.z); t[7] = (short)f2b(v1.w);
      *(bf16x8*)(As + i * 128 + ((u ^ (i & 7)) << 3)) = t;
    }
  }
  __syncthreads();

  const int lane = tid & 63, wid = tid >> 6;
  const int c15 = lane & 15, kg = lane >> 4;
  const int er0 = wid * 32;             // 32 edge-rows per wave
  f32x4 acc[2][8];
  #pragma unroll
  for (int a = 0; a < 2; a++)
    #pragma unroll
    for (int b = 0; b < 8; b++) acc[a][b] = (f32x4){0.f, 0.f, 0.f, 0.f};

  bf16x8 af[2][4];
  #pragma unroll
  for (int tr = 0; tr < 2; tr++)
    #pragma unroll
    for (int kk = 0; kk < 4; kk++) {
      int rr2 = er0 + tr * 16 + c15;
      int u = kk * 4 + kg;
      af[tr][kk] = *(const bf16x8*)(As + rr2 * 128 + ((u ^ (rr2 & 7)) << 3));
    }
  #pragma unroll
  for (int tc = 0; tc < 8; tc++) {
    bf16x8 bfr[4];
    #pragma unroll
    for (int kk = 0; kk < 4; kk++) {
      int hh = tc * 16 + c15;
      int u = kk * 4 + kg;
      bfr[kk] = *(const bf16x8*)(Bs + hh * 128 + ((u ^ (hh & 7)) << 3));
    }
    #pragma unroll
    for (int tr = 0; tr < 2; tr++)
      #pragma unroll
      for (int kk = 0; kk < 4; kk++)
        acc[tr][tc] = __builtin_amdgcn_mfma_f32_16x16x32_bf16(af[tr][kk], bfr[kk], acc[tr][tc], 0, 0, 0);
  }
  // scatter: C/D layout col=lane&15, row=(lane>>4)*4+reg
  #pragma unroll
  for (int tr = 0; tr < 2; tr++) {
    #pragma unroll
    for (int q = 0; q < 4; q++) {
      int er = er0 + tr * 16 + kg * 4 + q;
      int d = db[er]; float c = cb[er];
      float* po = out1 + d * 128 + c15;
      #pragma unroll
      for (int tc = 0; tc < 8; tc++)
        atomicAdd(po + tc * 16, acc[tr][tc][q] * c);
    }
  }
}

// ---------- relu + bias, f32 -> bf16 ----------
__global__ void relu_k(const float* __restrict__ out1, const float* __restrict__ mb1,
                       u16* __restrict__ h1) {
  int i = blockIdx.x * 256 + threadIdx.x;
  if (i >= NN * 128) return;
  float v = out1[i] + mb1[i & 127];
  h1[i] = f2b(v > 0.f ? v : 0.f);
}

// ---------- conv2: same structure, O=64, input already bf16 ----------
__global__ __launch_bounds__(256, 3) void conv2_k(
    const u16* __restrict__ hx, const int* __restrict__ src, const int* __restrict__ dst,
    const float* __restrict__ nout, const float* __restrict__ nin,
    const u16* __restrict__ W2T, float* __restrict__ out2)
{
  __shared__ __align__(16) u16 As[128 * 128];
  __shared__ __align__(16) u16 Bs[64 * 128];
  __shared__ float cb[128];
  __shared__ int   sb[128], db[128];

  const int tid = threadIdx.x;
  const int r = blockIdx.x >> 7, chunk = blockIdx.x & 127;
  const int ebase = r * EE + chunk * 128;

  if (tid < 128) {
    int s = src[ebase + tid], d = dst[ebase + tid];
    sb[tid] = s; db[tid] = d;
    cb[tid] = nout[r * NN + s] * nin[r * NN + d] * (1.0f / 64.0f);
  }
  {
    const uint4* Bg = (const uint4*)(W2T + (r << 13));
    #pragma unroll
    for (int it = 0; it < 4; ++it) {
      int idx = it * 256 + tid;        // 1024 16B units
      int h = idx >> 4, u = idx & 15;
      *(uint4*)(Bs + h * 128 + ((u ^ (h & 7)) << 3)) = Bg[idx];
    }
  }
  __syncthreads();
  {
    const int i = tid >> 1, half = tid & 1;
    const int s = sb[i];
    const uint4* xs = (const uint4*)(hx + s * 128 + half * 64);
    #pragma unroll
    for (int q = 0; q < 8; ++q) {
      int u = half * 8 + q;
      *(uint4*)(As + i * 128 + ((u ^ (i & 7)) << 3)) = xs[q];
    }
  }
  __syncthreads();

  const int lane = tid & 63, wid = tid >> 6;
  const int c15 = lane & 15, kg = lane >> 4;
  const int er0 = wid * 32;
  f32x4 acc[2][4];
  #pragma unroll
  for (int a = 0; a < 2; a++)
    #pragma unroll
    for (int b = 0; b < 4; b++) acc[a][b] = (f32x4){0.f, 0.f, 0.f, 0.f};

  bf16x8 af[2][4];
  #pragma unroll
  for (int tr = 0; tr < 2; tr++)
    #pragma unroll
    for (int kk = 0; kk < 4; kk++) {
      int rr2 = er0 + tr * 16 + c15;
      int u = kk * 4 + kg;
      af[tr][kk] = *(const bf16x8*)(As + rr2 * 128 + ((u ^ (rr2 & 7)) << 3));
    }
  #pragma unroll
  for (int tc = 0; tc < 4; tc++) {
    bf16x8 bfr[4];
    #pragma unroll
    for (int kk = 0; kk < 4; kk++) {
      int hh = tc * 16 + c15;
      int u = kk * 4 + kg;
      bfr[kk] = *(const bf16x8*)(Bs + hh * 128 + ((u ^ (hh & 7)) << 3));
    }
    #pragma unroll
    for (int tr = 0; tr < 2; tr++)
      #pragma unroll
      for (int kk = 0; kk < 4; kk++)
        acc[tr][tc] = __builtin_amdgcn_mfma_f32_16x16x32_bf16(af[tr][kk], bfr[kk], acc[tr][tc], 0, 0, 0);
  }
  #pragma unroll
  for (int tr = 0; tr < 2; tr++) {
    #pragma unroll
    for (int q = 0; q < 4; q++) {
      int er = er0 + tr * 16 + kg * 4 + q;
      int d = db[er]; float c = cb[er];
      float* po = out2 + d * 64 + c15;
      #pragma unroll
      for (int tc = 0; tc < 4; tc++)
        atomicAdd(po + tc * 16, acc[tr][tc][q] * c);
    }
  }
}

// ---------- BiLSTM single step (h0=c0=0 => w_hh unused; gates i,f,g,o; f unused) ----------
__global__ __launch_bounds__(256) void lstm_k(const float* __restrict__ out2, const float* __restrict__ mb2,
                                              const float* __restrict__ w_ih, const float* __restrict__ b_ih,
                                              const float* __restrict__ b_hh, float* __restrict__ out) {
  __shared__ float hs[4][64];
  int tid = threadIdx.x;
  int nl = tid >> 6, k = tid & 63;
  int n = blockIdx.x * 4 + nl;
  if (n < NN) hs[nl][k] = out2[n * 64 + k] + mb2[k];
  __syncthreads();
  if (n >= NN) return;
  int o = k, d = o >> 5, j = o & 31;
  const float* wb = w_ih + d * 128 * 64;
  float gi = b_ih[d * 128 + j]      + b_hh[d * 128 + j];
  float gg = b_ih[d * 128 + 64 + j] + b_hh[d * 128 + 64 + j];
  float go = b_ih[d * 128 + 96 + j] + b_hh[d * 128 + 96 + j];
  const float* wi = wb + j * 64;
  const float* wg = wb + (64 + j) * 64;
  const float* wo = wb + (96 + j) * 64;
  const float* h = hs[nl];
  #pragma unroll 8
  for (int kk = 0; kk < 64; kk++) {
    float hv = h[kk];
    gi = fmaf(hv, wi[kk], gi);
    gg = fmaf(hv, wg[kk], gg);
    go = fmaf(hv, wo[kk], go);
  }
  float c = sigm(gi) * tanhf(gg);
  out[n * 64 + o] = sigm(go) * tanhf(c);
}

extern "C" void kernel_launch(void* const* d_in, const int* in_sizes, int n_in,
                              void* d_out, int out_size, void* d_ws, size_t ws_size,
                              hipStream_t stream) {
  const int*   src  = (const int*)d_in[1];
  const int*   dst  = (const int*)d_in[2];
  const float* emb  = (const float*)d_in[3];
  const float* W1   = (const float*)d_in[4];
  const float* b1   = (const float*)d_in[5];
  const float* W2   = (const float*)d_in[6];
  const float* b2   = (const float*)d_in[7];
  const float* w_ih = (const float*)d_in[8];
  const float* b_ih = (const float*)d_in[10];
  const float* b_hh = (const float*)d_in[11];
  float* out = (float*)d_out;

  char* ws = (char*)d_ws;
  size_t off = 0;
  float* deg_out = (float*)(ws + off); off += (size_t)RR * NN * 4;
  float* deg_in  = (float*)(ws + off); off += (size_t)RR * NN * 4;
  float* out1    = (float*)(ws + off); off += (size_t)NN * 128 * 4;
  float* out2    = (float*)(ws + off); off += (size_t)NN * 64 * 4;
  size_t zbytes = off;                                  // accumulators + degrees: zero every call
  u16*   h1  = (u16*)(ws + off); off += (size_t)NN * 128 * 2;
  u16*   W1T = (u16*)(ws + off); off += (size_t)RR * 128 * 128 * 2;
  u16*   W2T = (u16*)(ws + off); off += (size_t)RR * 64 * 128 * 2;
  float* mb1 = (float*)(ws + off); off += 128 * 4;
  float* mb2 = (float*)(ws + off); off += 64 * 4;

  hipMemsetAsync(d_ws, 0, zbytes, stream);
  deg_k<<<RR * EE / 256, 256, 0, stream>>>(src, dst, deg_out, deg_in);
  norm_k<<<(RR * NN + 255) / 256, 256, 0, stream>>>(deg_out, deg_in);
  wt1_k<<<RR * 128 * 128 / 256, 256, 0, stream>>>(W1, W1T);
  wt2_k<<<RR * 64 * 128 / 256, 256, 0, stream>>>(W2, W2T);
  bias_k<<<1, 128, 0, stream>>>(b1, b2, mb1, mb2);
  conv1_k<<<RR * (EE / 128), 256, 0, stream>>>(emb, src, dst, deg_out, deg_in, W1T, out1);
  relu_k<<<(NN * 128 + 255) / 256, 256, 0, stream>>>(out1, mb1, h1);
  conv2_k<<<RR * (EE / 128), 256, 0, stream>>>(h1, src, dst, deg_out, deg_in, W2T, out2);
  lstm_k<<<(NN + 3) / 4, 256, 0, stream>>>(out2, mb2, w_ih, b_ih, b_hh, out);
}

// Round 2
// 516.250 us; speedup vs baseline: 1.6662x; 1.6662x over previous
//
#include <hip/hip_runtime.h>

#define NN 14541
#define RR 64
#define EE 16384
#define RN (RR * NN)              // 930624
#define SCAN_BLOCKS 3636
#define SCAN_LEN (SCAN_BLOCKS * 256)   // 930816 (pad >= RN)
#define NT 64
#define TILES 228                 // ceil(NN/64)
#define RGROUPS 4
#define RPG 16

typedef unsigned short u16;
typedef __attribute__((ext_vector_type(8))) short bf16x8;
typedef __attribute__((ext_vector_type(4))) float f32x4;

__device__ __forceinline__ u16 f2b(float f) {
  unsigned u = __builtin_bit_cast(unsigned, f);
  u += 0x7fffu + ((u >> 16) & 1u);
  return (u16)(u >> 16);
}
__device__ __forceinline__ float b2f(short h) {
  unsigned u = ((unsigned)(u16)h) << 16;
  return __builtin_bit_cast(float, u);
}
__device__ __forceinline__ float sigm(float x) { return 1.0f / (1.0f + expf(-x)); }

// ---------- integer degree count ----------
__global__ void deg_k(const int* __restrict__ src, const int* __restrict__ dst,
                      int* __restrict__ dout, int* __restrict__ din) {
  int i = blockIdx.x * 256 + threadIdx.x;   // RR*EE threads
  int r = i >> 14;
  atomicAdd(&dout[r * NN + src[i]], 1);
  atomicAdd(&din[r * NN + dst[i]], 1);
}

// ---------- norms: nout = deg_out^-1/2 ; nin = deg_in^-1/2 * (1/64 mean) ----------
__global__ void norm_k(const int* __restrict__ dout, const int* __restrict__ din,
                       float* __restrict__ nout, float* __restrict__ nin) {
  int i = blockIdx.x * 256 + threadIdx.x;
  if (i >= RN) return;
  int dO = dout[i], dI = din[i];
  nout[i] = dO > 0 ? rsqrtf((float)dO) : 1.0f;
  nin[i] = (dI > 0 ? rsqrtf((float)dI) : 1.0f) * 0.015625f;
}

// ---------- hierarchical exclusive scan of din (size SCAN_LEN) ----------
__global__ void scan_reduce(const int* __restrict__ din, int* __restrict__ bsum) {
  int v = din[blockIdx.x * 256 + threadIdx.x];
  #pragma unroll
  for (int o = 32; o > 0; o >>= 1) v += __shfl_down(v, o, 64);
  __shared__ int s[4];
  if ((threadIdx.x & 63) == 0) s[threadIdx.x >> 6] = v;
  __syncthreads();
  if (threadIdx.x == 0) bsum[blockIdx.x] = s[0] + s[1] + s[2] + s[3];
}

__global__ void scan_mid(int* __restrict__ bsum) {   // single block, exclusive in-place
  __shared__ int s[256];
  __shared__ int carry;
  if (threadIdx.x == 0) carry = 0;
  __syncthreads();
  for (int base = 0; base < SCAN_BLOCKS; base += 256) {
    int i = base + threadIdx.x;
    int v = (i < SCAN_BLOCKS) ? bsum[i] : 0;
    s[threadIdx.x] = v;
    __syncthreads();
    #pragma unroll
    for (int o = 1; o < 256; o <<= 1) {
      int t = (threadIdx.x >= o) ? s[threadIdx.x - o] : 0;
      __syncthreads();
      s[threadIdx.x] += t;
      __syncthreads();
    }
    int inc = s[threadIdx.x];
    if (i < SCAN_BLOCKS) bsum[i] = inc - v + carry;
    int tot = s[255];
    __syncthreads();
    if (threadIdx.x == 0) carry += tot;
    __syncthreads();
  }
}

__global__ void scan_final(const int* __restrict__ din, const int* __restrict__ bsum,
                           int* __restrict__ row_ptr, int* __restrict__ cursor) {
  __shared__ int s[256];
  int i = blockIdx.x * 256 + threadIdx.x;
  int v = din[i];
  s[threadIdx.x] = v;
  __syncthreads();
  #pragma unroll
  for (int o = 1; o < 256; o <<= 1) {
    int t = (threadIdx.x >= o) ? s[threadIdx.x - o] : 0;
    __syncthreads();
    s[threadIdx.x] += t;
    __syncthreads();
  }
  int exc = s[threadIdx.x] - v + bsum[blockIdx.x];
  row_ptr[i] = exc;
  cursor[i] = exc;
}

// ---------- CSR scatter: slot-assign edges sorted by (r,dst) ----------
__global__ void scatter_k(const int* __restrict__ src, const int* __restrict__ dst,
                          const float* __restrict__ nout, int* __restrict__ cursor,
                          int* __restrict__ ssrc, float* __restrict__ scoef) {
  int i = blockIdx.x * 256 + threadIdx.x;
  int r = i >> 14;
  int s = src[i], d = dst[i];
  int slot = atomicAdd(&cursor[r * NN + d], 1);
  ssrc[slot] = s;
  scoef[slot] = nout[r * NN + s];
}

// ---------- weight transpose + bf16 ----------
__global__ void wt1_k(const float* __restrict__ W1, u16* __restrict__ W1T) {
  int idx = blockIdx.x * 256 + threadIdx.x;      // RR*128*128
  int r = idx >> 14, rem = idx & 16383, h = rem >> 7, k = rem & 127;
  W1T[idx] = f2b(W1[(r << 14) + (k << 7) + h]);
}
__global__ void wt2_k(const float* __restrict__ W2, u16* __restrict__ W2T) {
  int idx = blockIdx.x * 256 + threadIdx.x;      // RR*64*128
  int r = idx >> 13, rem = idx & 8191, o = rem >> 7, k = rem & 127;
  W2T[idx] = f2b(W2[(r << 13) + (k << 6) + o]);
}
__global__ void bias_k(const float* __restrict__ b1, const float* __restrict__ b2,
                       float* __restrict__ mb1, float* __restrict__ mb2) {
  int t = threadIdx.x;
  if (t < 128) { float s = 0.f; for (int r = 0; r < RR; r++) s += b1[r * 128 + t]; mb1[t] = s * (1.f/64.f); }
  if (t < 64)  { float s = 0.f; for (int r = 0; r < RR; r++) s += b2[r * 64 + t];  mb2[t] = s * (1.f/64.f); }
}
__global__ void embbf_k(const float* __restrict__ emb, u16* __restrict__ emb_bf) {
  int i = blockIdx.x * 256 + threadIdx.x;
  if (i < NN * 128) emb_bf[i] = f2b(emb[i]);
}

// ---------- conv1: node-centric, block = 64 dst rows x 16 relations, acc in regs ----------
__global__ __launch_bounds__(256, 3) void conv1_k(
    const u16* __restrict__ emb_bf, const int* __restrict__ row_ptr,
    const int* __restrict__ ssrc, const float* __restrict__ scoef,
    const float* __restrict__ nin, const u16* __restrict__ W1T,
    float* __restrict__ out1)
{
  __shared__ __align__(16) u16 As[NT * 128];    // 16 KB, XOR-swizzled 16B units
  __shared__ __align__(16) u16 Bs[128 * 128];   // 32 KB, swizzled

  const int tid = threadIdx.x;
  const int t = blockIdx.x % TILES, g = blockIdx.x / TILES;
  const int nb = t * NT;
  const int lane = tid & 63, wid = tid >> 6, c15 = lane & 15, kg = lane >> 4;
  const int rowi = tid >> 2, q = tid & 3;       // A-build: 4 threads per row
  const int n = nb + rowi;

  f32x4 acc[8];
  #pragma unroll
  for (int b = 0; b < 8; b++) acc[b] = (f32x4){0.f, 0.f, 0.f, 0.f};

  for (int rr = 0; rr < RPG; ++rr) {
    const int r = g * RPG + rr;
    // stage B = W1T[r] (32 KB) swizzled
    const uint4* Bg = (const uint4*)(W1T + (r << 14));
    #pragma unroll
    for (int it = 0; it < 8; ++it) {
      int idx = it * 256 + tid;
      int h = idx >> 4, u = idx & 15;
      *(uint4*)(Bs + h * 128 + ((u ^ (h & 7)) << 3)) = Bg[idx];
    }
    // build A row: f32 gather-aggregate of CSR neighbors, then bf16 pack
    {
      float a[32];
      #pragma unroll
      for (int j = 0; j < 32; j++) a[j] = 0.f;
      if (n < NN) {
        const int rn = r * NN + n;
        const int p1 = row_ptr[rn + 1];
        for (int p = row_ptr[rn]; p < p1; ++p) {
          const float c = scoef[p];
          const bf16x8* xs = (const bf16x8*)(emb_bf + (size_t)ssrc[p] * 128 + q * 32);
          #pragma unroll
          for (int w = 0; w < 4; w++) {
            bf16x8 v = xs[w];
            #pragma unroll
            for (int j = 0; j < 8; j++) a[w * 8 + j] = fmaf(c, b2f(v[j]), a[w * 8 + j]);
          }
        }
        const float si = nin[rn];
        #pragma unroll
        for (int j = 0; j < 32; j++) a[j] *= si;
      }
      #pragma unroll
      for (int w = 0; w < 4; w++) {
        bf16x8 tt;
        #pragma unroll
        for (int j = 0; j < 8; j++) tt[j] = (short)f2b(a[w * 8 + j]);
        const int u = q * 4 + w;
        *(bf16x8*)(As + rowi * 128 + ((u ^ (rowi & 7)) << 3)) = tt;
      }
    }
    __syncthreads();
    // GEMM: wave owns 16 rows x 128 cols
    {
      bf16x8 af[4];
      const int er = wid * 16 + c15;
      #pragma unroll
      for (int kk = 0; kk < 4; kk++) {
        int u = kk * 4 + kg;
        af[kk] = *(const bf16x8*)(As + er * 128 + ((u ^ (er & 7)) << 3));
      }
      #pragma unroll
      for (int tc = 0; tc < 8; tc++) {
        const int hh = tc * 16 + c15;
        #pragma unroll
        for (int kk = 0; kk < 4; kk++) {
          int u = kk * 4 + kg;
          bf16x8 bfr = *(const bf16x8*)(Bs + hh * 128 + ((u ^ (hh & 7)) << 3));
          acc[tc] = __builtin_amdgcn_mfma_f32_16x16x32_bf16(af[kk], bfr, acc[tc], 0, 0, 0);
        }
      }
    }
    __syncthreads();
  }
  // epilogue: one atomic per (node, col) per relation-group
  #pragma unroll
  for (int qi = 0; qi < 4; qi++) {
    const int nn2 = nb + wid * 16 + kg * 4 + qi;
    if (nn2 < NN) {
      float* po = out1 + (size_t)nn2 * 128 + c15;
      #pragma unroll
      for (int tc = 0; tc < 8; tc++)
        atomicAdd(po + tc * 16, acc[tc][qi]);
    }
  }
}

// ---------- relu + bias -> bf16 ----------
__global__ void relu_k(const float* __restrict__ out1, const float* __restrict__ mb1,
                       u16* __restrict__ h1) {
  int i = blockIdx.x * 256 + threadIdx.x;
  if (i >= NN * 128) return;
  float v = out1[i] + mb1[i & 127];
  h1[i] = f2b(v > 0.f ? v : 0.f);
}

// ---------- conv2: same structure, 64-wide output ----------
__global__ __launch_bounds__(256, 3) void conv2_k(
    const u16* __restrict__ h1, const int* __restrict__ row_ptr,
    const int* __restrict__ ssrc, const float* __restrict__ scoef,
    const float* __restrict__ nin, const u16* __restrict__ W2T,
    float* __restrict__ out2)
{
  __shared__ __align__(16) u16 As[NT * 128];    // 16 KB
  __shared__ __align__(16) u16 Bs[64 * 128];    // 16 KB

  const int tid = threadIdx.x;
  const int t = blockIdx.x % TILES, g = blockIdx.x / TILES;
  const int nb = t * NT;
  const int lane = tid & 63, wid = tid >> 6, c15 = lane & 15, kg = lane >> 4;
  const int rowi = tid >> 2, q = tid & 3;
  const int n = nb + rowi;

  f32x4 acc[4];
  #pragma unroll
  for (int b = 0; b < 4; b++) acc[b] = (f32x4){0.f, 0.f, 0.f, 0.f};

  for (int rr = 0; rr < RPG; ++rr) {
    const int r = g * RPG + rr;
    const uint4* Bg = (const uint4*)(W2T + (r << 13));
    #pragma unroll
    for (int it = 0; it < 4; ++it) {
      int idx = it * 256 + tid;
      int h = idx >> 4, u = idx & 15;
      *(uint4*)(Bs + h * 128 + ((u ^ (h & 7)) << 3)) = Bg[idx];
    }
    {
      float a[32];
      #pragma unroll
      for (int j = 0; j < 32; j++) a[j] = 0.f;
      if (n < NN) {
        const int rn = r * NN + n;
        const int p1 = row_ptr[rn + 1];
        for (int p = row_ptr[rn]; p < p1; ++p) {
          const float c = scoef[p];
          const bf16x8* xs = (const bf16x8*)(h1 + (size_t)ssrc[p] * 128 + q * 32);
          #pragma unroll
          for (int w = 0; w < 4; w++) {
            bf16x8 v = xs[w];
            #pragma unroll
            for (int j = 0; j < 8; j++) a[w * 8 + j] = fmaf(c, b2f(v[j]), a[w * 8 + j]);
          }
        }
        const float si = nin[rn];
        #pragma unroll
        for (int j = 0; j < 32; j++) a[j] *= si;
      }
      #pragma unroll
      for (int w = 0; w < 4; w++) {
        bf16x8 tt;
        #pragma unroll
        for (int j = 0; j < 8; j++) tt[j] = (short)f2b(a[w * 8 + j]);
        const int u = q * 4 + w;
        *(bf16x8*)(As + rowi * 128 + ((u ^ (rowi & 7)) << 3)) = tt;
      }
    }
    __syncthreads();
    {
      bf16x8 af[4];
      const int er = wid * 16 + c15;
      #pragma unroll
      for (int kk = 0; kk < 4; kk++) {
        int u = kk * 4 + kg;
        af[kk] = *(const bf16x8*)(As + er * 128 + ((u ^ (er & 7)) << 3));
      }
      #pragma unroll
      for (int tc = 0; tc < 4; tc++) {
        const int hh = tc * 16 + c15;
        #pragma unroll
        for (int kk = 0; kk < 4; kk++) {
          int u = kk * 4 + kg;
          bf16x8 bfr = *(const bf16x8*)(Bs + hh * 128 + ((u ^ (hh & 7)) << 3));
          acc[tc] = __builtin_amdgcn_mfma_f32_16x16x32_bf16(af[kk], bfr, acc[tc], 0, 0, 0);
        }
      }
    }
    __syncthreads();
  }
  #pragma unroll
  for (int qi = 0; qi < 4; qi++) {
    const int nn2 = nb + wid * 16 + kg * 4 + qi;
    if (nn2 < NN) {
      float* po = out2 + (size_t)nn2 * 64 + c15;
      #pragma unroll
      for (int tc = 0; tc < 4; tc++)
        atomicAdd(po + tc * 16, acc[tc][qi]);
    }
  }
}

// ---------- BiLSTM single step ----------
__global__ __launch_bounds__(256) void lstm_k(const float* __restrict__ out2, const float* __restrict__ mb2,
                                              const float* __restrict__ w_ih, const float* __restrict__ b_ih,
                                              const float* __restrict__ b_hh, float* __restrict__ out) {
  __shared__ float hs[4][64];
  int tid = threadIdx.x;
  int nl = tid >> 6, k = tid & 63;
  int n = blockIdx.x * 4 + nl;
  if (n < NN) hs[nl][k] = out2[n * 64 + k] + mb2[k];
  __syncthreads();
  if (n >= NN) return;
  int o = k, d = o >> 5, j = o & 31;
  const float* wb = w_ih + d * 128 * 64;
  float gi = b_ih[d * 128 + j]      + b_hh[d * 128 + j];
  float gg = b_ih[d * 128 + 64 + j] + b_hh[d * 128 + 64 + j];
  float go = b_ih[d * 128 + 96 + j] + b_hh[d * 128 + 96 + j];
  const float* wi = wb + j * 64;
  const float* wg = wb + (64 + j) * 64;
  const float* wo = wb + (96 + j) * 64;
  const float* h = hs[nl];
  #pragma unroll 8
  for (int kk = 0; kk < 64; kk++) {
    float hv = h[kk];
    gi = fmaf(hv, wi[kk], gi);
    gg = fmaf(hv, wg[kk], gg);
    go = fmaf(hv, wo[kk], go);
  }
  float c = sigm(gi) * tanhf(gg);
  out[n * 64 + o] = sigm(go) * tanhf(c);
}

extern "C" void kernel_launch(void* const* d_in, const int* in_sizes, int n_in,
                              void* d_out, int out_size, void* d_ws, size_t ws_size,
                              hipStream_t stream) {
  const int*   src  = (const int*)d_in[1];
  const int*   dst  = (const int*)d_in[2];
  const float* emb  = (const float*)d_in[3];
  const float* W1   = (const float*)d_in[4];
  const float* b1   = (const float*)d_in[5];
  const float* W2   = (const float*)d_in[6];
  const float* b2   = (const float*)d_in[7];
  const float* w_ih = (const float*)d_in[8];
  const float* b_ih = (const float*)d_in[10];
  const float* b_hh = (const float*)d_in[11];
  float* out = (float*)d_out;

  char* ws = (char*)d_ws;
  size_t off = 0;
  int*   din_i  = (int*)(ws + off);   off += (size_t)SCAN_LEN * 4;
  int*   dout_i = (int*)(ws + off);   off += (size_t)RN * 4;
  float* out1   = (float*)(ws + off); off += (size_t)NN * 128 * 4;
  float* out2   = (float*)(ws + off); off += (size_t)NN * 64 * 4;
  size_t zbytes = off;                // zero every call (degrees + pad + accumulators)
  float* nout   = (float*)(ws + off); off += (size_t)RN * 4;
  float* nin    = (float*)(ws + off); off += (size_t)RN * 4;
  int*   row_ptr= (int*)(ws + off);   off += (size_t)(SCAN_LEN + 256) * 4;
  int*   cursor = (int*)(ws + off);   off += (size_t)SCAN_LEN * 4;
  int*   ssrc   = (int*)(ws + off);   off += (size_t)RR * EE * 4;
  float* scoef  = (float*)(ws + off); off += (size_t)RR * EE * 4;
  u16*   emb_bf = (u16*)(ws + off);   off += (size_t)NN * 128 * 2;
  u16*   h1     = (u16*)(ws + off);   off += (size_t)NN * 128 * 2;
  u16*   W1T    = (u16*)(ws + off);   off += (size_t)RR * 128 * 128 * 2;
  u16*   W2T    = (u16*)(ws + off);   off += (size_t)RR * 64 * 128 * 2;
  int*   bsum   = (int*)(ws + off);   off += 4096 * 4;
  float* mb1    = (float*)(ws + off); off += 512;
  float* mb2    = (float*)(ws + off); off += 256;

  hipMemsetAsync(d_ws, 0, zbytes, stream);
  deg_k<<<RR * EE / 256, 256, 0, stream>>>(src, dst, dout_i, din_i);
  norm_k<<<SCAN_BLOCKS, 256, 0, stream>>>(dout_i, din_i, nout, nin);
  wt1_k<<<RR * 128 * 128 / 256, 256, 0, stream>>>(W1, W1T);
  wt2_k<<<RR * 64 * 128 / 256, 256, 0, stream>>>(W2, W2T);
  bias_k<<<1, 128, 0, stream>>>(b1, b2, mb1, mb2);
  embbf_k<<<(NN * 128 + 255) / 256, 256, 0, stream>>>(emb, emb_bf);
  scan_reduce<<<SCAN_BLOCKS, 256, 0, stream>>>(din_i, bsum);
  scan_mid<<<1, 256, 0, stream>>>(bsum);
  scan_final<<<SCAN_BLOCKS, 256, 0, stream>>>(din_i, bsum, row_ptr, cursor);
  scatter_k<<<RR * EE / 256, 256, 0, stream>>>(src, dst, nout, cursor, ssrc, scoef);
  conv1_k<<<TILES * RGROUPS, 256, 0, stream>>>(emb_bf, row_ptr, ssrc, scoef, nin, W1T, out1);
  relu_k<<<(NN * 128 + 255) / 256, 256, 0, stream>>>(out1, mb1, h1);
  conv2_k<<<TILES * RGROUPS, 256, 0, stream>>>(h1, row_ptr, ssrc, scoef, nin, W2T, out2);
  lstm_k<<<(NN + 3) / 4, 256, 0, stream>>>(out2, mb2, w_ih, b_ih, b_hh, out);
}

// Round 3
// 514.463 us; speedup vs baseline: 1.6720x; 1.0035x over previous
//
#include <hip/hip_runtime.h>

#define NN 14541
#define RR 64
#define EE 16384
#define RN (RR * NN)              // 930624
#define SCAN_BLOCKS 3636
#define SCAN_LEN (SCAN_BLOCKS * 256)   // 930816 (pad >= RN)
#define NT 64
#define TILES 228                 // ceil(NN/64)
#define RGROUPS 4
#define RPG 16

typedef unsigned short u16;
typedef __attribute__((ext_vector_type(8))) short bf16x8;
typedef __attribute__((ext_vector_type(4))) float f32x4;

__device__ __forceinline__ u16 f2b(float f) {
  unsigned u = __builtin_bit_cast(unsigned, f);
  u += 0x7fffu + ((u >> 16) & 1u);
  return (u16)(u >> 16);
}
__device__ __forceinline__ float b2f(short h) {
  unsigned u = ((unsigned)(u16)h) << 16;
  return __builtin_bit_cast(float, u);
}
__device__ __forceinline__ float sigm(float x) { return 1.0f / (1.0f + expf(-x)); }

__device__ __forceinline__ void gload_lds16(const void* g, void* l) {
  __builtin_amdgcn_global_load_lds(
      (const __attribute__((address_space(1))) unsigned int*)g,
      (__attribute__((address_space(3))) unsigned int*)l, 16, 0, 0);
}

// ---------- integer degree count ----------
__global__ void deg_k(const int* __restrict__ src, const int* __restrict__ dst,
                      int* __restrict__ dout, int* __restrict__ din) {
  int i = blockIdx.x * 256 + threadIdx.x;   // RR*EE threads
  int r = i >> 14;
  atomicAdd(&dout[r * NN + src[i]], 1);
  atomicAdd(&din[r * NN + dst[i]], 1);
}

// ---------- norms: nout = deg_out^-1/2 ; nin = deg_in^-1/2 * (1/64 mean) ----------
__global__ void norm_k(const int* __restrict__ dout, const int* __restrict__ din,
                       float* __restrict__ nout, float* __restrict__ nin) {
  int i = blockIdx.x * 256 + threadIdx.x;
  if (i >= RN) return;
  int dO = dout[i], dI = din[i];
  nout[i] = dO > 0 ? rsqrtf((float)dO) : 1.0f;
  nin[i] = (dI > 0 ? rsqrtf((float)dI) : 1.0f) * 0.015625f;
}

// ---------- hierarchical exclusive scan of din (size SCAN_LEN) ----------
__global__ void scan_reduce(const int* __restrict__ din, int* __restrict__ bsum) {
  int v = din[blockIdx.x * 256 + threadIdx.x];
  #pragma unroll
  for (int o = 32; o > 0; o >>= 1) v += __shfl_down(v, o, 64);
  __shared__ int s[4];
  if ((threadIdx.x & 63) == 0) s[threadIdx.x >> 6] = v;
  __syncthreads();
  if (threadIdx.x == 0) bsum[blockIdx.x] = s[0] + s[1] + s[2] + s[3];
}

__global__ void scan_mid(int* __restrict__ bsum) {   // single block, exclusive in-place
  __shared__ int s[256];
  __shared__ int carry;
  if (threadIdx.x == 0) carry = 0;
  __syncthreads();
  for (int base = 0; base < SCAN_BLOCKS; base += 256) {
    int i = base + threadIdx.x;
    int v = (i < SCAN_BLOCKS) ? bsum[i] : 0;
    s[threadIdx.x] = v;
    __syncthreads();
    #pragma unroll
    for (int o = 1; o < 256; o <<= 1) {
      int t = (threadIdx.x >= o) ? s[threadIdx.x - o] : 0;
      __syncthreads();
      s[threadIdx.x] += t;
      __syncthreads();
    }
    int inc = s[threadIdx.x];
    if (i < SCAN_BLOCKS) bsum[i] = inc - v + carry;
    int tot = s[255];
    __syncthreads();
    if (threadIdx.x == 0) carry += tot;
    __syncthreads();
  }
}

__global__ void scan_final(const int* __restrict__ din, const int* __restrict__ bsum,
                           int* __restrict__ row_ptr, int* __restrict__ cursor) {
  __shared__ int s[256];
  int i = blockIdx.x * 256 + threadIdx.x;
  int v = din[i];
  s[threadIdx.x] = v;
  __syncthreads();
  #pragma unroll
  for (int o = 1; o < 256; o <<= 1) {
    int t = (threadIdx.x >= o) ? s[threadIdx.x - o] : 0;
    __syncthreads();
    s[threadIdx.x] += t;
    __syncthreads();
  }
  int exc = s[threadIdx.x] - v + bsum[blockIdx.x];
  row_ptr[i] = exc;
  cursor[i] = exc;
}

// ---------- CSR scatter: slot-assign edges sorted by (r,dst) ----------
__global__ void scatter_k(const int* __restrict__ src, const int* __restrict__ dst,
                          const float* __restrict__ nout, int* __restrict__ cursor,
                          int* __restrict__ ssrc, float* __restrict__ scoef) {
  int i = blockIdx.x * 256 + threadIdx.x;
  int r = i >> 14;
  int s = src[i], d = dst[i];
  int slot = atomicAdd(&cursor[r * NN + d], 1);
  ssrc[slot] = s;
  scoef[slot] = nout[r * NN + s];
}

// ---------- weight transpose + bf16, PRE-SWIZZLED for linear global_load_lds staging ----------
// LDS physical 16B-unit p = h*16 + v must hold logical k-chunk u = v ^ (h&7) of W^T row h.
__global__ void wt1_k(const float* __restrict__ W1, u16* __restrict__ W1T) {
  int idx = blockIdx.x * 256 + threadIdx.x;      // RR*128*128 u16 elems
  int r = idx >> 14, e = idx & 16383;
  int h = e >> 7, v = (e >> 3) & 15, j = e & 7;
  int k = ((v ^ (h & 7)) << 3) + j;
  W1T[idx] = f2b(W1[(r << 14) + (k << 7) + h]);
}
__global__ void wt2_k(const float* __restrict__ W2, u16* __restrict__ W2T) {
  int idx = blockIdx.x * 256 + threadIdx.x;      // RR*64*128 u16 elems
  int r = idx >> 13, e = idx & 8191;
  int h = e >> 7, v = (e >> 3) & 15, j = e & 7;
  int k = ((v ^ (h & 7)) << 3) + j;
  W2T[idx] = f2b(W2[(r << 13) + (k << 6) + h]);
}
__global__ void bias_k(const float* __restrict__ b1, const float* __restrict__ b2,
                       float* __restrict__ mb1, float* __restrict__ mb2) {
  int t = threadIdx.x;
  if (t < 128) { float s = 0.f; for (int r = 0; r < RR; r++) s += b1[r * 128 + t]; mb1[t] = s * (1.f/64.f); }
  if (t < 64)  { float s = 0.f; for (int r = 0; r < RR; r++) s += b2[r * 64 + t];  mb2[t] = s * (1.f/64.f); }
}
__global__ void embbf_k(const float* __restrict__ emb, u16* __restrict__ emb_bf) {
  int i = blockIdx.x * 256 + threadIdx.x;
  if (i < NN * 128) emb_bf[i] = f2b(emb[i]);
}

// ---------- conv1: node-centric; A-fragments gathered directly into owner lanes (no As LDS) ----------
__global__ __launch_bounds__(256, 4) void conv1_k(
    const u16* __restrict__ emb_bf, const int* __restrict__ row_ptr,
    const int* __restrict__ ssrc, const float* __restrict__ scoef,
    const float* __restrict__ nin, const u16* __restrict__ W1T,
    float* __restrict__ out1)
{
  __shared__ __align__(16) u16 Bs[128 * 128];   // 32 KB (content arrives pre-swizzled)

  const int tid = threadIdx.x;
  const int t = blockIdx.x % TILES, g = blockIdx.x / TILES;
  const int nb = t * NT;
  const int lane = tid & 63, wid = tid >> 6, c15 = lane & 15, kg = lane >> 4;
  const int n = nb + wid * 16 + c15;            // this lane's gather row
  const int gbase = g * RPG;

  f32x4 acc[8];
  #pragma unroll
  for (int b = 0; b < 8; b++) acc[b] = (f32x4){0.f, 0.f, 0.f, 0.f};

  // rolling row_ptr state: current (rc), next (rn); prefetched first-2 neighbors (ps/pc)
  int rc0 = row_ptr[gbase * NN + n];
  int rc1 = row_ptr[gbase * NN + n + 1];
  int rn0 = row_ptr[(gbase + 1) * NN + n];
  int rn1 = row_ptr[(gbase + 1) * NN + n + 1];
  int ps0 = 0, ps1 = 0; float pc0 = 0.f, pc1 = 0.f;
  {
    int d = rc1 - rc0;
    if (d > 0) { ps0 = ssrc[rc0]; pc0 = scoef[rc0]; }
    if (d > 1) { ps1 = ssrc[rc0 + 1]; pc1 = scoef[rc0 + 1]; }
  }

  for (int rr = 0; rr < RPG; ++rr) {
    const int r = gbase + rr;
    // stage B via global_load_lds: 8 x 16B per lane, linear LDS dest
    {
      const u16* src_g = W1T + (r << 14);
      #pragma unroll
      for (int it = 0; it < 8; ++it) {
        gload_lds16(src_g + (it * 256 + tid) * 8, (u16*)Bs + (it * 256 + wid * 64) * 8);
      }
    }
    // prefetch row_ptr for rr+2
    int f0 = 0, f1 = 0;
    if (rr + 2 < RPG) { f0 = row_ptr[(r + 2) * NN + n]; f1 = row_ptr[(r + 2) * NN + n + 1]; }
    // prefetch first-2 neighbors of rr+1
    int qs0 = 0, qs1 = 0; float qc0 = 0.f, qc1 = 0.f;
    {
      int nd = rn1 - rn0;
      if (nd > 0) { qs0 = ssrc[rn0]; qc0 = scoef[rn0]; }
      if (nd > 1) { qs1 = ssrc[rn0 + 1]; qc1 = scoef[rn0 + 1]; }
    }
    const float si = (n < NN) ? nin[r * NN + n] : 0.f;
    // gather this lane's A-fragment: k-chunks kk*32 + kg*8 .. +7
    float a[4][8];
    #pragma unroll
    for (int kk = 0; kk < 4; kk++)
      #pragma unroll
      for (int j = 0; j < 8; j++) a[kk][j] = 0.f;
    const int d = rc1 - rc0;
    if (d > 0) {
      const bf16x8* xr = (const bf16x8*)(emb_bf + (size_t)ps0 * 128);
      #pragma unroll
      for (int kk = 0; kk < 4; kk++) {
        bf16x8 v = xr[kk * 4 + kg];
        #pragma unroll
        for (int j = 0; j < 8; j++) a[kk][j] = fmaf(pc0, b2f(v[j]), a[kk][j]);
      }
    }
    if (d > 1) {
      const bf16x8* xr = (const bf16x8*)(emb_bf + (size_t)ps1 * 128);
      #pragma unroll
      for (int kk = 0; kk < 4; kk++) {
        bf16x8 v = xr[kk * 4 + kg];
        #pragma unroll
        for (int j = 0; j < 8; j++) a[kk][j] = fmaf(pc1, b2f(v[j]), a[kk][j]);
      }
    }
    for (int p = rc0 + 2; p < rc1; ++p) {
      int s = ssrc[p]; float c = scoef[p];
      const bf16x8* xr = (const bf16x8*)(emb_bf + (size_t)s * 128);
      #pragma unroll
      for (int kk = 0; kk < 4; kk++) {
        bf16x8 v = xr[kk * 4 + kg];
        #pragma unroll
        for (int j = 0; j < 8; j++) a[kk][j] = fmaf(c, b2f(v[j]), a[kk][j]);
      }
    }
    // scale + pack to bf16 fragments
    bf16x8 af[4];
    #pragma unroll
    for (int kk = 0; kk < 4; kk++) {
      #pragma unroll
      for (int j = 0; j < 8; j++) af[kk][j] = (short)f2b(a[kk][j] * si);
    }
    __syncthreads();   // B staged (drains vmcnt) for all waves
    #pragma unroll
    for (int tc = 0; tc < 8; tc++) {
      const int hh = tc * 16 + c15;
      #pragma unroll
      for (int kk = 0; kk < 4; kk++) {
        int u = kk * 4 + kg;
        bf16x8 bfr = *(const bf16x8*)(Bs + hh * 128 + ((u ^ (hh & 7)) << 3));
        acc[tc] = __builtin_amdgcn_mfma_f32_16x16x32_bf16(af[kk], bfr, acc[tc], 0, 0, 0);
      }
    }
    // rotate pipeline state
    rc0 = rn0; rc1 = rn1; rn0 = f0; rn1 = f1;
    ps0 = qs0; ps1 = qs1; pc0 = qc0; pc1 = qc1;
    if (rr + 1 < RPG) __syncthreads();   // all waves done reading Bs before next stage
  }
  // epilogue: one atomic per (node, col) per relation-group
  #pragma unroll
  for (int qi = 0; qi < 4; qi++) {
    const int nn2 = nb + wid * 16 + kg * 4 + qi;
    if (nn2 < NN) {
      float* po = out1 + (size_t)nn2 * 128 + c15;
      #pragma unroll
      for (int tc = 0; tc < 8; tc++)
        atomicAdd(po + tc * 16, acc[tc][qi]);
    }
  }
}

// ---------- relu + bias -> bf16 ----------
__global__ void relu_k(const float* __restrict__ out1, const float* __restrict__ mb1,
                       u16* __restrict__ h1) {
  int i = blockIdx.x * 256 + threadIdx.x;
  if (i >= NN * 128) return;
  float v = out1[i] + mb1[i & 127];
  h1[i] = f2b(v > 0.f ? v : 0.f);
}

// ---------- conv2: same structure, 64-wide output ----------
__global__ __launch_bounds__(256, 5) void conv2_k(
    const u16* __restrict__ h1, const int* __restrict__ row_ptr,
    const int* __restrict__ ssrc, const float* __restrict__ scoef,
    const float* __restrict__ nin, const u16* __restrict__ W2T,
    float* __restrict__ out2)
{
  __shared__ __align__(16) u16 Bs[64 * 128];    // 16 KB

  const int tid = threadIdx.x;
  const int t = blockIdx.x % TILES, g = blockIdx.x / TILES;
  const int nb = t * NT;
  const int lane = tid & 63, wid = tid >> 6, c15 = lane & 15, kg = lane >> 4;
  const int n = nb + wid * 16 + c15;
  const int gbase = g * RPG;

  f32x4 acc[4];
  #pragma unroll
  for (int b = 0; b < 4; b++) acc[b] = (f32x4){0.f, 0.f, 0.f, 0.f};

  int rc0 = row_ptr[gbase * NN + n];
  int rc1 = row_ptr[gbase * NN + n + 1];
  int rn0 = row_ptr[(gbase + 1) * NN + n];
  int rn1 = row_ptr[(gbase + 1) * NN + n + 1];
  int ps0 = 0, ps1 = 0; float pc0 = 0.f, pc1 = 0.f;
  {
    int d = rc1 - rc0;
    if (d > 0) { ps0 = ssrc[rc0]; pc0 = scoef[rc0]; }
    if (d > 1) { ps1 = ssrc[rc0 + 1]; pc1 = scoef[rc0 + 1]; }
  }

  for (int rr = 0; rr < RPG; ++rr) {
    const int r = gbase + rr;
    {
      const u16* src_g = W2T + (r << 13);
      #pragma unroll
      for (int it = 0; it < 4; ++it) {
        gload_lds16(src_g + (it * 256 + tid) * 8, (u16*)Bs + (it * 256 + wid * 64) * 8);
      }
    }
    int f0 = 0, f1 = 0;
    if (rr + 2 < RPG) { f0 = row_ptr[(r + 2) * NN + n]; f1 = row_ptr[(r + 2) * NN + n + 1]; }
    int qs0 = 0, qs1 = 0; float qc0 = 0.f, qc1 = 0.f;
    {
      int nd = rn1 - rn0;
      if (nd > 0) { qs0 = ssrc[rn0]; qc0 = scoef[rn0]; }
      if (nd > 1) { qs1 = ssrc[rn0 + 1]; qc1 = scoef[rn0 + 1]; }
    }
    const float si = (n < NN) ? nin[r * NN + n] : 0.f;
    float a[4][8];
    #pragma unroll
    for (int kk = 0; kk < 4; kk++)
      #pragma unroll
      for (int j = 0; j < 8; j++) a[kk][j] = 0.f;
    const int d = rc1 - rc0;
    if (d > 0) {
      const bf16x8* xr = (const bf16x8*)(h1 + (size_t)ps0 * 128);
      #pragma unroll
      for (int kk = 0; kk < 4; kk++) {
        bf16x8 v = xr[kk * 4 + kg];
        #pragma unroll
        for (int j = 0; j < 8; j++) a[kk][j] = fmaf(pc0, b2f(v[j]), a[kk][j]);
      }
    }
    if (d > 1) {
      const bf16x8* xr = (const bf16x8*)(h1 + (size_t)ps1 * 128);
      #pragma unroll
      for (int kk = 0; kk < 4; kk++) {
        bf16x8 v = xr[kk * 4 + kg];
        #pragma unroll
        for (int j = 0; j < 8; j++) a[kk][j] = fmaf(pc1, b2f(v[j]), a[kk][j]);
      }
    }
    for (int p = rc0 + 2; p < rc1; ++p) {
      int s = ssrc[p]; float c = scoef[p];
      const bf16x8* xr = (const bf16x8*)(h1 + (size_t)s * 128);
      #pragma unroll
      for (int kk = 0; kk < 4; kk++) {
        bf16x8 v = xr[kk * 4 + kg];
        #pragma unroll
        for (int j = 0; j < 8; j++) a[kk][j] = fmaf(c, b2f(v[j]), a[kk][j]);
      }
    }
    bf16x8 af[4];
    #pragma unroll
    for (int kk = 0; kk < 4; kk++) {
      #pragma unroll
      for (int j = 0; j < 8; j++) af[kk][j] = (short)f2b(a[kk][j] * si);
    }
    __syncthreads();
    #pragma unroll
    for (int tc = 0; tc < 4; tc++) {
      const int hh = tc * 16 + c15;
      #pragma unroll
      for (int kk = 0; kk < 4; kk++) {
        int u = kk * 4 + kg;
        bf16x8 bfr = *(const bf16x8*)(Bs + hh * 128 + ((u ^ (hh & 7)) << 3));
        acc[tc] = __builtin_amdgcn_mfma_f32_16x16x32_bf16(af[kk], bfr, acc[tc], 0, 0, 0);
      }
    }
    rc0 = rn0; rc1 = rn1; rn0 = f0; rn1 = f1;
    ps0 = qs0; ps1 = qs1; pc0 = qc0; pc1 = qc1;
    if (rr + 1 < RPG) __syncthreads();
  }
  #pragma unroll
  for (int qi = 0; qi < 4; qi++) {
    const int nn2 = nb + wid * 16 + kg * 4 + qi;
    if (nn2 < NN) {
      float* po = out2 + (size_t)nn2 * 64 + c15;
      #pragma unroll
      for (int tc = 0; tc < 4; tc++)
        atomicAdd(po + tc * 16, acc[tc][qi]);
    }
  }
}

// ---------- BiLSTM single step ----------
__global__ __launch_bounds__(256) void lstm_k(const float* __restrict__ out2, const float* __restrict__ mb2,
                                              const float* __restrict__ w_ih, const float* __restrict__ b_ih,
                                              const float* __restrict__ b_hh, float* __restrict__ out) {
  __shared__ float hs[4][64];
  int tid = threadIdx.x;
  int nl = tid >> 6, k = tid & 63;
  int n = blockIdx.x * 4 + nl;
  if (n < NN) hs[nl][k] = out2[n * 64 + k] + mb2[k];
  __syncthreads();
  if (n >= NN) return;
  int o = k, d = o >> 5, j = o & 31;
  const float* wb = w_ih + d * 128 * 64;
  float gi = b_ih[d * 128 + j]      + b_hh[d * 128 + j];
  float gg = b_ih[d * 128 + 64 + j] + b_hh[d * 128 + 64 + j];
  float go = b_ih[d * 128 + 96 + j] + b_hh[d * 128 + 96 + j];
  const float* wi = wb + j * 64;
  const float* wg = wb + (64 + j) * 64;
  const float* wo = wb + (96 + j) * 64;
  const float* h = hs[nl];
  #pragma unroll 8
  for (int kk = 0; kk < 64; kk++) {
    float hv = h[kk];
    gi = fmaf(hv, wi[kk], gi);
    gg = fmaf(hv, wg[kk], gg);
    go = fmaf(hv, wo[kk], go);
  }
  float c = sigm(gi) * tanhf(gg);
  out[n * 64 + o] = sigm(go) * tanhf(c);
}

extern "C" void kernel_launch(void* const* d_in, const int* in_sizes, int n_in,
                              void* d_out, int out_size, void* d_ws, size_t ws_size,
                              hipStream_t stream) {
  const int*   src  = (const int*)d_in[1];
  const int*   dst  = (const int*)d_in[2];
  const float* emb  = (const float*)d_in[3];
  const float* W1   = (const float*)d_in[4];
  const float* b1   = (const float*)d_in[5];
  const float* W2   = (const float*)d_in[6];
  const float* b2   = (const float*)d_in[7];
  const float* w_ih = (const float*)d_in[8];
  const float* b_ih = (const float*)d_in[10];
  const float* b_hh = (const float*)d_in[11];
  float* out = (float*)d_out;

  char* ws = (char*)d_ws;
  size_t off = 0;
  int*   din_i  = (int*)(ws + off);   off += (size_t)SCAN_LEN * 4;
  int*   dout_i = (int*)(ws + off);   off += (size_t)RN * 4;
  float* out1   = (float*)(ws + off); off += (size_t)NN * 128 * 4;
  float* out2   = (float*)(ws + off); off += (size_t)NN * 64 * 4;
  size_t zbytes = off;                // zero every call (degrees + pad + accumulators)
  float* nout   = (float*)(ws + off); off += (size_t)RN * 4;
  float* nin    = (float*)(ws + off); off += (size_t)RN * 4;
  int*   row_ptr= (int*)(ws + off);   off += (size_t)(SCAN_LEN + 256) * 4;
  int*   cursor = (int*)(ws + off);   off += (size_t)SCAN_LEN * 4;
  int*   ssrc   = (int*)(ws + off);   off += (size_t)RR * EE * 4;
  float* scoef  = (float*)(ws + off); off += (size_t)RR * EE * 4;
  u16*   emb_bf = (u16*)(ws + off);   off += (size_t)NN * 128 * 2;
  u16*   h1     = (u16*)(ws + off);   off += (size_t)NN * 128 * 2;
  u16*   W1T    = (u16*)(ws + off);   off += (size_t)RR * 128 * 128 * 2;
  u16*   W2T    = (u16*)(ws + off);   off += (size_t)RR * 64 * 128 * 2;
  int*   bsum   = (int*)(ws + off);   off += 4096 * 4;
  float* mb1    = (float*)(ws + off); off += 512;
  float* mb2    = (float*)(ws + off); off += 256;

  hipMemsetAsync(d_ws, 0, zbytes, stream);
  deg_k<<<RR * EE / 256, 256, 0, stream>>>(src, dst, dout_i, din_i);
  norm_k<<<SCAN_BLOCKS, 256, 0, stream>>>(dout_i, din_i, nout, nin);
  wt1_k<<<RR * 128 * 128 / 256, 256, 0, stream>>>(W1, W1T);
  wt2_k<<<RR * 64 * 128 / 256, 256, 0, stream>>>(W2, W2T);
  bias_k<<<1, 128, 0, stream>>>(b1, b2, mb1, mb2);
  embbf_k<<<(NN * 128 + 255) / 256, 256, 0, stream>>>(emb, emb_bf);
  scan_reduce<<<SCAN_BLOCKS, 256, 0, stream>>>(din_i, bsum);
  scan_mid<<<1, 256, 0, stream>>>(bsum);
  scan_final<<<SCAN_BLOCKS, 256, 0, stream>>>(din_i, bsum, row_ptr, cursor);
  scatter_k<<<RR * EE / 256, 256, 0, stream>>>(src, dst, nout, cursor, ssrc, scoef);
  conv1_k<<<TILES * RGROUPS, 256, 0, stream>>>(emb_bf, row_ptr, ssrc, scoef, nin, W1T, out1);
  relu_k<<<(NN * 128 + 255) / 256, 256, 0, stream>>>(out1, mb1, h1);
  conv2_k<<<TILES * RGROUPS, 256, 0, stream>>>(h1, row_ptr, ssrc, scoef, nin, W2T, out2);
  lstm_k<<<(NN + 3) / 4, 256, 0, stream>>>(out2, mb2, w_ih, b_ih, b_hh, out);
}